// Round 1
// baseline (603.303 us; speedup 1.0000x reference)
//
#include <hip/hip_runtime.h>

#define N_SEG 256
#define HIDDEN 512

// Order-preserving float -> uint mapping for atomicMax on floats
__device__ __forceinline__ unsigned map_f(float f) {
    unsigned b = __float_as_uint(f);
    return (b & 0x80000000u) ? ~b : (b | 0x80000000u);
}
__device__ __forceinline__ float unmap_f(unsigned m) {
    unsigned b = (m & 0x80000000u) ? (m & 0x7FFFFFFFu) : ~m;
    return __uint_as_float(b);
}

// Zero out[], init per-segment max (mapped -inf) and denom
__global__ void init_kernel(float* __restrict__ out, unsigned* __restrict__ gmaxu,
                            float* __restrict__ denom) {
    int i = blockIdx.x * blockDim.x + threadIdx.x;
    if (i < N_SEG * HIDDEN) out[i] = 0.0f;
    if (i < N_SEG) {
        gmaxu[i] = map_f(-__builtin_inff());
        denom[i] = 0.0f;
    }
}

// One wave (64 lanes) per node: gate[i] = dot(x[i,:], W) + b; segment atomicMax
__global__ __launch_bounds__(256) void gate_kernel(
    const float* __restrict__ x, const int* __restrict__ batch,
    const float* __restrict__ W, const float* __restrict__ bptr,
    float* __restrict__ gate, unsigned* __restrict__ gmaxu, int n) {
    int wave = (int)((blockIdx.x * (unsigned)blockDim.x + threadIdx.x) >> 6);
    int lane = threadIdx.x & 63;
    // W fragment lives in 8 VGPRs (same 8 values reused for every node)
    float4 w0 = *(const float4*)(W + lane * 8);
    float4 w1 = *(const float4*)(W + lane * 8 + 4);
    if (wave >= n) return;  // uniform per wave
    const float* xr = x + (size_t)wave * HIDDEN + lane * 8;
    float4 a0 = *(const float4*)(xr);
    float4 a1 = *(const float4*)(xr + 4);
    float s = a0.x * w0.x + a0.y * w0.y + a0.z * w0.z + a0.w * w0.w
            + a1.x * w1.x + a1.y * w1.y + a1.z * w1.z + a1.w * w1.w;
    #pragma unroll
    for (int off = 32; off; off >>= 1) s += __shfl_xor(s, off, 64);
    if (lane == 0) {
        float g = s + bptr[0];
        gate[wave] = g;
        atomicMax(&gmaxu[batch[wave]], map_f(g));
    }
}

// denom[s] = sum exp(gate - gmax[s])
__global__ __launch_bounds__(256) void denom_kernel(
    const float* __restrict__ gate, const int* __restrict__ batch,
    const unsigned* __restrict__ gmaxu, float* __restrict__ denom, int n) {
    int i = blockIdx.x * blockDim.x + threadIdx.x;
    if (i >= n) return;
    int b = batch[i];
    float e = __expf(gate[i] - unmap_f(gmaxu[b]));
    atomicAdd(&denom[b], e);
}

// One block per (segment, chunk of 8): register-accumulate 2 columns/thread
#define CHUNKS 8
__global__ __launch_bounds__(256) void pool_kernel(
    const float* __restrict__ x, const int* __restrict__ batch,
    const float* __restrict__ gate, const unsigned* __restrict__ gmaxu,
    const float* __restrict__ denom, float* __restrict__ out, int n) {
    int s = blockIdx.x >> 3;
    int c = blockIdx.x & 7;
    // lower_bound(batch, s) and lower_bound(batch, s+1) — batch is sorted
    int lo = 0, hi = n;
    while (lo < hi) { int mid = (lo + hi) >> 1; if (batch[mid] < s) lo = mid + 1; else hi = mid; }
    int seg_start = lo;
    hi = n;
    while (lo < hi) { int mid = (lo + hi) >> 1; if (batch[mid] < s + 1) lo = mid + 1; else hi = mid; }
    int seg_end = lo;
    int len = seg_end - seg_start;
    if (len == 0) return;  // empty segment: out stays zero
    int i0 = seg_start + (int)(((long long)len * c) >> 3);
    int i1 = seg_start + (int)(((long long)len * (c + 1)) >> 3);
    float gmax = unmap_f(gmaxu[s]);
    float inv_d = 1.0f / (denom[s] + 1e-16f);
    int t = threadIdx.x;
    float acc0 = 0.0f, acc1 = 0.0f;
    for (int i = i0; i < i1; ++i) {
        float alpha = __expf(gate[i] - gmax) * inv_d;  // scalar, broadcast loads
        const float* xr = x + (size_t)i * HIDDEN;
        acc0 += alpha * xr[t];
        acc1 += alpha * xr[t + 256];
    }
    atomicAdd(&out[s * HIDDEN + t], acc0);
    atomicAdd(&out[s * HIDDEN + t + 256], acc1);
}

extern "C" void kernel_launch(void* const* d_in, const int* in_sizes, int n_in,
                              void* d_out, int out_size, void* d_ws, size_t ws_size,
                              hipStream_t stream) {
    const float* x     = (const float*)d_in[0];
    const int*   batch = (const int*)d_in[1];
    const float* W     = (const float*)d_in[2];
    const float* b     = (const float*)d_in[3];
    int n = in_sizes[1];
    float* out = (float*)d_out;

    float*    gate  = (float*)d_ws;
    unsigned* gmaxu = (unsigned*)((char*)d_ws + (size_t)n * sizeof(float));
    float*    denom = (float*)((char*)d_ws + (size_t)n * sizeof(float) + N_SEG * sizeof(unsigned));

    init_kernel<<<(N_SEG * HIDDEN + 255) / 256, 256, 0, stream>>>(out, gmaxu, denom);
    gate_kernel<<<(n + 3) / 4, 256, 0, stream>>>(x, batch, W, b, gate, gmaxu, n);
    denom_kernel<<<(n + 255) / 256, 256, 0, stream>>>(gate, batch, gmaxu, denom, n);
    pool_kernel<<<N_SEG * CHUNKS, 256, 0, stream>>>(x, batch, gate, gmaxu, denom, out, n);
}

// Round 2
// 81.575 us; speedup vs baseline: 7.3957x; 7.3957x over previous
//
#include <hip/hip_runtime.h>

#define N_SEG 256
#define HIDDEN 512

__device__ __forceinline__ float wave_max64(float v) {
    #pragma unroll
    for (int off = 32; off; off >>= 1) v = fmaxf(v, __shfl_xor(v, off, 64));
    return v;
}
__device__ __forceinline__ float wave_sum64(float v) {
    #pragma unroll
    for (int off = 32; off; off >>= 1) v += __shfl_xor(v, off, 64);
    return v;
}

// Pass A: one wave (64 lanes) per node: gate[i] = dot(x[i,:], W) + b. No atomics.
__global__ __launch_bounds__(256) void gate_kernel(
    const float* __restrict__ x, const float* __restrict__ W,
    const float* __restrict__ bptr, float* __restrict__ gate, int n) {
    int wave = (int)((blockIdx.x * (unsigned)blockDim.x + threadIdx.x) >> 6);
    int lane = threadIdx.x & 63;
    float4 w0 = *(const float4*)(W + lane * 8);
    float4 w1 = *(const float4*)(W + lane * 8 + 4);
    if (wave >= n) return;  // uniform per wave
    const float* xr = x + (size_t)wave * HIDDEN + lane * 8;
    float4 a0 = *(const float4*)(xr);
    float4 a1 = *(const float4*)(xr + 4);
    float s = a0.x * w0.x + a0.y * w0.y + a0.z * w0.z + a0.w * w0.w
            + a1.x * w1.x + a1.y * w1.y + a1.z * w1.z + a1.w * w1.w;
    s = wave_sum64(s);
    if (lane == 0) gate[wave] = s + bptr[0];
}

// Pass B: one block per segment. Binary-search bounds in sorted batch,
// block-reduce max and sum(exp), write gmax/inv_denom, zero out-row. No atomics.
__global__ __launch_bounds__(256) void segstat_kernel(
    const float* __restrict__ gate, const int* __restrict__ batch,
    float* __restrict__ gmax, float* __restrict__ inv_denom,
    float* __restrict__ out, int n) {
    int s = blockIdx.x;
    int t = threadIdx.x;
    // zero this segment's output row (pool accumulates with atomics)
    for (int j = t; j < HIDDEN; j += 256) out[s * HIDDEN + j] = 0.0f;

    int lo = 0, hi = n;
    while (lo < hi) { int mid = (lo + hi) >> 1; if (batch[mid] < s) lo = mid + 1; else hi = mid; }
    int seg_start = lo;
    hi = n;
    while (lo < hi) { int mid = (lo + hi) >> 1; if (batch[mid] < s + 1) lo = mid + 1; else hi = mid; }
    int seg_end = lo;

    __shared__ float smax[4];
    __shared__ float ssum[4];
    int lane = t & 63, wid = t >> 6;

    float m = -__builtin_inff();
    for (int i = seg_start + t; i < seg_end; i += 256) m = fmaxf(m, gate[i]);
    m = wave_max64(m);
    if (lane == 0) smax[wid] = m;
    __syncthreads();
    float gm = fmaxf(fmaxf(smax[0], smax[1]), fmaxf(smax[2], smax[3]));

    float acc = 0.0f;
    for (int i = seg_start + t; i < seg_end; i += 256) acc += __expf(gate[i] - gm);
    acc = wave_sum64(acc);
    if (lane == 0) ssum[wid] = acc;
    __syncthreads();
    if (t == 0) {
        float d = ssum[0] + ssum[1] + ssum[2] + ssum[3];
        gmax[s] = gm;
        inv_denom[s] = 1.0f / (d + 1e-16f);
    }
}

// Pass C: one block per (segment, chunk of 8); each thread owns 2 adjacent
// columns (float2 loads), register-accumulate, one atomicAdd pair at the end.
#define CHUNKS 8
__global__ __launch_bounds__(256) void pool_kernel(
    const float* __restrict__ x, const int* __restrict__ batch,
    const float* __restrict__ gate, const float* __restrict__ gmax,
    const float* __restrict__ inv_denom, float* __restrict__ out, int n) {
    int s = blockIdx.x >> 3;
    int c = blockIdx.x & 7;
    int lo = 0, hi = n;
    while (lo < hi) { int mid = (lo + hi) >> 1; if (batch[mid] < s) lo = mid + 1; else hi = mid; }
    int seg_start = lo;
    hi = n;
    while (lo < hi) { int mid = (lo + hi) >> 1; if (batch[mid] < s + 1) lo = mid + 1; else hi = mid; }
    int seg_end = lo;
    int len = seg_end - seg_start;
    if (len == 0) return;  // out row already zeroed in segstat
    int i0 = seg_start + (int)(((long long)len * c) >> 3);
    int i1 = seg_start + (int)(((long long)len * (c + 1)) >> 3);
    float gm = gmax[s];
    float inv_d = inv_denom[s];
    int t = threadIdx.x;
    float accx = 0.0f, accy = 0.0f;
    for (int i = i0; i < i1; ++i) {
        float alpha = __expf(gate[i] - gm) * inv_d;  // broadcast scalar load
        float2 v = *(const float2*)(x + (size_t)i * HIDDEN + 2 * t);
        accx += alpha * v.x;
        accy += alpha * v.y;
    }
    atomicAdd(&out[s * HIDDEN + 2 * t], accx);
    atomicAdd(&out[s * HIDDEN + 2 * t + 1], accy);
}

extern "C" void kernel_launch(void* const* d_in, const int* in_sizes, int n_in,
                              void* d_out, int out_size, void* d_ws, size_t ws_size,
                              hipStream_t stream) {
    const float* x     = (const float*)d_in[0];
    const int*   batch = (const int*)d_in[1];
    const float* W     = (const float*)d_in[2];
    const float* b     = (const float*)d_in[3];
    int n = in_sizes[1];
    float* out = (float*)d_out;

    float* gate      = (float*)d_ws;
    float* gmax      = (float*)((char*)d_ws + (size_t)n * sizeof(float));
    float* inv_denom = gmax + N_SEG;

    gate_kernel<<<(n + 3) / 4, 256, 0, stream>>>(x, W, b, gate, n);
    segstat_kernel<<<N_SEG, 256, 0, stream>>>(gate, batch, gmax, inv_denom, out, n);
    pool_kernel<<<N_SEG * CHUNKS, 256, 0, stream>>>(x, batch, gate, gmax, inv_denom, out, n);
}

// Round 3
// 47.090 us; speedup vs baseline: 12.8116x; 1.7323x over previous
//
#include <hip/hip_runtime.h>

#define N_SEG 256
#define HIDDEN 512
#define CHUNKS 8
#define NEG_INF (-__builtin_inff())

// seg_off[s] = lower_bound(batch, s), s in [0, 256]; batch is sorted.
__global__ void bounds_kernel(const int* __restrict__ batch, int* __restrict__ seg_off, int n) {
    int s = blockIdx.x * blockDim.x + threadIdx.x;
    if (s > N_SEG) return;
    int lo = 0, hi = n;
    while (lo < hi) { int mid = (lo + hi) >> 1; if (batch[mid] < s) lo = mid + 1; else hi = mid; }
    seg_off[s] = lo;
}

// One block per (segment, chunk): 4 waves, each wave owns rows strided by 4.
// Per row: wave reads the full 512-float row (8 floats/lane), computes
// gate = dot(row, W) via in-register W + shfl butterfly (bias cancels in
// softmax), then online-softmax accumulates into 8 regs/lane.
// Block merges its 4 waves via LDS and writes one partial (m, d, acc[512]).
__global__ __launch_bounds__(256) void fused_kernel(
    const float* __restrict__ x, const float* __restrict__ W,
    const int* __restrict__ seg_off,
    float* __restrict__ pm, float* __restrict__ pd, float* __restrict__ pacc) {
    int s = blockIdx.x >> 3, c = blockIdx.x & 7;
    int t = threadIdx.x, lane = t & 63, w = t >> 6;
    int ss = seg_off[s], se = seg_off[s + 1];
    int len = se - ss;
    int i0 = ss + (int)(((long long)len * c) >> 3);
    int i1 = ss + (int)(((long long)len * (c + 1)) >> 3);
    int pidx = blockIdx.x;  // s*CHUNKS + c

    if (i0 >= i1) {  // empty chunk
        if (t == 0) { pm[pidx] = NEG_INF; pd[pidx] = 0.0f; }
        for (int j = t; j < HIDDEN; j += 256) pacc[(size_t)pidx * HIDDEN + j] = 0.0f;
        return;
    }

    float4 w0 = *(const float4*)(W + lane * 8);
    float4 w1 = *(const float4*)(W + lane * 8 + 4);
    float m = NEG_INF, d = 0.0f;
    float acc[8] = {0, 0, 0, 0, 0, 0, 0, 0};

    int i = i0 + w;
    bool have = i < i1;   // wave-uniform
    float4 a0, a1;
    if (have) {
        const float* xr = x + (size_t)i * HIDDEN + lane * 8;
        a0 = *(const float4*)xr; a1 = *(const float4*)(xr + 4);
    }
    while (have) {
        int inext = i + 4;
        bool hnext = inext < i1;
        float4 b0, b1;
        if (hnext) {  // 1-deep prefetch of next row
            const float* xr = x + (size_t)inext * HIDDEN + lane * 8;
            b0 = *(const float4*)xr; b1 = *(const float4*)(xr + 4);
        }
        float g = a0.x * w0.x + a0.y * w0.y + a0.z * w0.z + a0.w * w0.w
                + a1.x * w1.x + a1.y * w1.y + a1.z * w1.z + a1.w * w1.w;
        #pragma unroll
        for (int off = 32; off; off >>= 1) g += __shfl_xor(g, off, 64);
        float mn = fmaxf(m, g);
        float scale = __expf(m - mn);  // = 0 on first row (m = -inf), 1 if max unchanged
        float p = __expf(g - mn);
        d = d * scale + p;
        acc[0] = acc[0] * scale + p * a0.x;  acc[1] = acc[1] * scale + p * a0.y;
        acc[2] = acc[2] * scale + p * a0.z;  acc[3] = acc[3] * scale + p * a0.w;
        acc[4] = acc[4] * scale + p * a1.x;  acc[5] = acc[5] * scale + p * a1.y;
        acc[6] = acc[6] * scale + p * a1.z;  acc[7] = acc[7] * scale + p * a1.w;
        m = mn;
        a0 = b0; a1 = b1; i = inext; have = hnext;
    }

    // ---- block-level softmax merge of the 4 waves via LDS ----
    __shared__ float sm[4], sd[4];
    __shared__ float sacc[4][HIDDEN];  // 8 KB
    if (lane == 0) sm[w] = m;
    __syncthreads();
    float M = fmaxf(fmaxf(sm[0], sm[1]), fmaxf(sm[2], sm[3]));  // finite (chunk non-empty)
    float scale = (m == NEG_INF) ? 0.0f : __expf(m - M);        // empty wave contributes 0
    if (lane == 0) sd[w] = d * scale;
    #pragma unroll
    for (int j = 0; j < 8; ++j) sacc[w][lane * 8 + j] = acc[j] * scale;
    __syncthreads();
    if (t == 0) { pm[pidx] = M; pd[pidx] = sd[0] + sd[1] + sd[2] + sd[3]; }
    for (int j = t; j < HIDDEN; j += 256)
        pacc[(size_t)pidx * HIDDEN + j] = sacc[0][j] + sacc[1][j] + sacc[2][j] + sacc[3][j];
}

// One block per segment: softmax-merge the 8 chunk partials, divide, write out.
__global__ __launch_bounds__(256) void merge_kernel(
    const float* __restrict__ pm, const float* __restrict__ pd,
    const float* __restrict__ pacc, float* __restrict__ out) {
    int s = blockIdx.x, t = threadIdx.x;
    float M = NEG_INF;
    #pragma unroll
    for (int c = 0; c < CHUNKS; ++c) M = fmaxf(M, pm[s * CHUNKS + c]);
    float wts[CHUNKS];
    float D = 0.0f;
    #pragma unroll
    for (int c = 0; c < CHUNKS; ++c) {
        float mc = pm[s * CHUNKS + c];
        float wc = (mc == NEG_INF) ? 0.0f : __expf(mc - M);  // also guards M = -inf (empty segment)
        wts[c] = wc;
        D += pd[s * CHUNKS + c] * wc;
    }
    float invD = 1.0f / (D + 1e-16f);
    #pragma unroll
    for (int rep = 0; rep < 2; ++rep) {
        int j = t + rep * 256;
        float num = 0.0f;
        #pragma unroll
        for (int c = 0; c < CHUNKS; ++c)
            num += pacc[((size_t)(s * CHUNKS + c)) * HIDDEN + j] * wts[c];
        out[s * HIDDEN + j] = num * invD;  // empty segment -> 0
    }
}

extern "C" void kernel_launch(void* const* d_in, const int* in_sizes, int n_in,
                              void* d_out, int out_size, void* d_ws, size_t ws_size,
                              hipStream_t stream) {
    const float* x     = (const float*)d_in[0];
    const int*   batch = (const int*)d_in[1];
    const float* W     = (const float*)d_in[2];
    int n = in_sizes[1];
    float* out = (float*)d_out;

    // ws layout: pm[2048] | pd[2048] | pacc[2048*512] | seg_off[257]
    float* pm   = (float*)d_ws;
    float* pd   = pm + N_SEG * CHUNKS;
    float* pacc = pd + N_SEG * CHUNKS;
    int* seg_off = (int*)(pacc + (size_t)N_SEG * CHUNKS * HIDDEN);

    bounds_kernel<<<2, 256, 0, stream>>>(batch, seg_off, n);
    fused_kernel<<<N_SEG * CHUNKS, 256, 0, stream>>>(x, W, seg_off, pm, pd, pacc);
    merge_kernel<<<N_SEG, 256, 0, stream>>>(pm, pd, pacc, out);
}